// Round 8
// baseline (186.611 us; speedup 1.0000x reference)
//
#include <hip/hip_runtime.h>

#define B_SZ    64
#define S_LEN   448
#define D_MODEL 1024
#define N_HEAD  16
#define CHUNK   4
#define NCH     112   // 112 * 4 = 448

typedef float f4 __attribute__((ext_vector_type(4)));

// ws layout (float offsets)
#define PARTU_OFF  0          // 24*65536 = 1,572,864 (gemm k-split partials)
#define QKV_OFF    1572864    // [3][64][1024] = 196,608 (q+bq, knew, vnew+bv)
#define ACC_OFF    1769472    // [64*112][1024] = 7,340,032
#define ML_OFF     9109504    // [64*112][32]   = 229,376
#define WV_OFF     9338880    // 65,536            (total ~37.6 MB)

// ---------------------------------------------------------------------------
// GEMM partial: P[(mat*8+kt)][b][n] = sum_{k in kt-range} X[b][k] * W[k][n]
// ---------------------------------------------------------------------------
__global__ __launch_bounds__(256) void gemm_part(
    const float* __restrict__ X,
    const float* __restrict__ W0, const float* __restrict__ W1,
    const float* __restrict__ W2,
    float* __restrict__ P)
{
    const int nt  = blockIdx.x;
    const int kt  = blockIdx.y;
    const int mat = blockIdx.z;
    const float* __restrict__ W = (mat == 0) ? W0 : ((mat == 1) ? W1 : W2);

    const int t  = threadIdx.x;
    const int n  = nt * 64 + (t & 63);
    const int b0 = __builtin_amdgcn_readfirstlane((t >> 6) * 16);
    const int k0 = kt * 128;

    float acc[16];
#pragma unroll
    for (int j = 0; j < 16; ++j) acc[j] = 0.f;

#pragma unroll 8
    for (int k = k0; k < k0 + 128; ++k) {
        const float w = W[k * D_MODEL + n];
#pragma unroll
        for (int j = 0; j < 16; ++j)
            acc[j] += X[(b0 + j) * D_MODEL + k] * w;
    }

    float* p = P + (size_t)(mat * 8 + kt) * (B_SZ * D_MODEL);
#pragma unroll
    for (int j = 0; j < 16; ++j)
        p[(b0 + j) * D_MODEL + n] = acc[j];
}

// materialize q(+bq), knew, vnew(+bv) from the k-split partials
__global__ __launch_bounds__(256) void prep(
    const float* __restrict__ P, const float* __restrict__ bq,
    const float* __restrict__ bv, float* __restrict__ qkv)
{
    const int i   = blockIdx.x * 256 + threadIdx.x;   // < 196608
    const int mat = i >> 16;
    const int r   = i & 65535;
    const int d   = r & (D_MODEL - 1);
    float s = (mat == 0) ? bq[d] : ((mat == 2) ? bv[d] : 0.f);
#pragma unroll
    for (int kt = 0; kt < 8; ++kt)
        s += P[(size_t)(mat * 8 + kt) * 65536 + r];
    qkv[i] = s;
}

// reduce 8 k-partials + bias -> final out projection
__global__ __launch_bounds__(256) void reduce_out(
    const float* __restrict__ P, const float* __restrict__ bo,
    float* __restrict__ out)
{
    const int i = blockIdx.x * 256 + threadIdx.x;     // < 65536
    float s = bo[i & (D_MODEL - 1)];
#pragma unroll
    for (int kt = 0; kt < 8; ++kt)
        s += P[(size_t)kt * 65536 + i];
    out[i] = s;
}

// ---------------------------------------------------------------------------
// Fused three-phase stream, SLIDING-WINDOW grid: 7168 address-ordered blocks
// (bid = b*112 + c), 4 rows per block. ~2048 resident -> ~33 MB moving window.
// Thread t: cols 4t..4t+3, head h = t>>4. Per-block chunk softmax partials.
// ---------------------------------------------------------------------------
__global__ __launch_bounds__(256) void fused_stream(
    const float* __restrict__ kcache, const float* __restrict__ vcache,
    const float* __restrict__ qkv,   // [3][64][1024]: q, knew, vnew
    const float* __restrict__ amask, const int* __restrict__ idxp,
    float* __restrict__ kout, float* __restrict__ vout,
    float* __restrict__ accws, float* __restrict__ mlws)
{
    const int bid = blockIdx.x;          // address-ordered: b major, c minor
    const int b   = bid / NCH;
    const int c   = bid % NCH;
    const int t   = threadIdx.x;
    const int col = t * 4;
    const int h   = t >> 4;
    const int l16 = t & 15;
    const int idx = idxp[0];
    const int s0  = c * CHUNK;

    const f4 q = *(const f4*)(qkv + b * D_MODEL + col);
    f4 knew = (f4)0.f, vnew = (f4)0.f;
    if (idx >= s0 && idx < s0 + CHUNK) {
        knew = *(const f4*)(qkv + (size_t)(B_SZ + b) * D_MODEL + col);
        vnew = *(const f4*)(qkv + (size_t)(2 * B_SZ + b) * D_MODEL + col);
    }

    const size_t base = ((size_t)b * S_LEN + s0) * D_MODEL + col;

    // Phase 1: K stream (4 independent rows) + dot partials
    float p[CHUNK];
#pragma unroll
    for (int r = 0; r < CHUNK; ++r) {
        f4 k4 = *(const f4*)(kcache + base + (size_t)r * D_MODEL);
        if (s0 + r == idx) k4 = knew;
        __builtin_nontemporal_store(k4, (f4*)(kout + base + (size_t)r * D_MODEL));
        p[r] = q.x * k4.x + q.y * k4.y + q.z * k4.z + q.w * k4.w;
    }

    // Phase 2: 4 independent 16-lane butterflies + chunk softmax in registers
#pragma unroll
    for (int r = 0; r < CHUNK; ++r) {
        float v = p[r];
        v += __shfl_xor(v, 1);
        v += __shfl_xor(v, 2);
        v += __shfl_xor(v, 4);
        v += __shfl_xor(v, 8);
        p[r] = v * 0.125f + amask[s0 + r];
    }
    float m = p[0];
#pragma unroll
    for (int r = 1; r < CHUNK; ++r) m = fmaxf(m, p[r]);
    float l = 0.f;
#pragma unroll
    for (int r = 0; r < CHUNK; ++r) { p[r] = __expf(p[r] - m); l += p[r]; }

    // Phase 3: V stream + weighted accumulate
    f4 acc = (f4)0.f;
#pragma unroll
    for (int r = 0; r < CHUNK; ++r) {
        f4 v4 = *(const f4*)(vcache + base + (size_t)r * D_MODEL);
        if (s0 + r == idx) v4 = vnew;
        __builtin_nontemporal_store(v4, (f4*)(vout + base + (size_t)r * D_MODEL));
        acc.x += p[r] * v4.x;
        acc.y += p[r] * v4.y;
        acc.z += p[r] * v4.z;
        acc.w += p[r] * v4.w;
    }

    // per-block partials: accws[bid][col] (= [b][c][h][d]), mlws[bid][h*2]
    *(f4*)(accws + (size_t)bid * D_MODEL + col) = acc;
    if (l16 == 0) {
        mlws[bid * 32 + h * 2]     = m;
        mlws[bid * 32 + h * 2 + 1] = l;
    }
}

// combine 112 chunk partials -> wv[b][h*64+d]
__global__ __launch_bounds__(256) void combine(
    const float* __restrict__ accws, const float* __restrict__ mlws,
    float* __restrict__ wvws)
{
    const int t = threadIdx.x;
    const int w = blockIdx.x * 4 + (t >> 6);   // (b*16+h), 0..1023
    const int b = w >> 4, h = w & 15;
    const int d = t & 63;

    float M = -1e30f;
#pragma unroll 8
    for (int c = 0; c < NCH; ++c)
        M = fmaxf(M, mlws[(b * NCH + c) * 32 + h * 2]);
    float L = 0.f, O = 0.f;
#pragma unroll 8
    for (int c = 0; c < NCH; ++c) {
        const float f = __expf(mlws[(b * NCH + c) * 32 + h * 2] - M);
        L += mlws[(b * NCH + c) * 32 + h * 2 + 1] * f;
        O += accws[(size_t)(b * NCH + c) * D_MODEL + h * 64 + d] * f;
    }
    wvws[b * D_MODEL + h * 64 + d] = O / L;
}

// ---------------------------------------------------------------------------
extern "C" void kernel_launch(void* const* d_in, const int* in_sizes, int n_in,
                              void* d_out, int out_size, void* d_ws, size_t ws_size,
                              hipStream_t stream) {
    const float* x      = (const float*)d_in[0];
    const float* kcache = (const float*)d_in[1];
    const float* vcache = (const float*)d_in[2];
    const int*   idxp   = (const int*)d_in[3];
    const float* amask  = (const float*)d_in[4];
    const float* Wq     = (const float*)d_in[5];
    const float* bq     = (const float*)d_in[6];
    const float* Wk     = (const float*)d_in[7];
    const float* Wv     = (const float*)d_in[8];
    const float* bv     = (const float*)d_in[9];
    const float* Wo     = (const float*)d_in[10];
    const float* bo     = (const float*)d_in[11];

    float* out  = (float*)d_out;                 // [64][1024]
    float* kout = out + 65536;                   // [64][448][1024]
    float* vout = kout + (size_t)B_SZ * S_LEN * D_MODEL;

    float* ws    = (float*)d_ws;
    float* partU = ws + PARTU_OFF;
    float* qkv   = ws + QKV_OFF;
    float* accws = ws + ACC_OFF;
    float* mlws  = ws + ML_OFF;
    float* wvws  = ws + WV_OFF;

    // q/k/v projections (k-split partials)
    gemm_part<<<dim3(16, 8, 3), 256, 0, stream>>>(x, Wq, Wk, Wv, partU);

    // q(+bq) / knew / vnew
    prep<<<768, 256, 0, stream>>>(partU, bq, bv, qkv);

    // fused cache update + attention partials (sliding-window grid)
    fused_stream<<<B_SZ * NCH, 256, 0, stream>>>(
        kcache, vcache, qkv, amask, idxp, kout, vout, accws, mlws);

    // softmax combine over 112 chunks -> wv
    combine<<<256, 256, 0, stream>>>(accws, mlws, wvws);

    // output projection (writes partU slots 0-7; partials dead after prep)
    gemm_part<<<dim3(16, 8, 1), 256, 0, stream>>>(wvws, Wo, Wo, Wo, partU);
    reduce_out<<<256, 256, 0, stream>>>(partU, bo, out);
}